// Round 7
// baseline (127.422 us; speedup 1.0000x reference)
//
#include <hip/hip_runtime.h>
#include <hip/hip_bf16.h>
#include <math.h>

#define Bb   16
#define Ll   2048
#define Dd   1024
#define OSo  64
#define NCc  256
#define LABh 1024
#define BN_EPS 1e-5f

typedef short s8v  __attribute__((ext_vector_type(8)));   // 8 bf16 = 4 VGPR
typedef short s4v  __attribute__((ext_vector_type(4)));
typedef float f32x4 __attribute__((ext_vector_type(4)));

__device__ __forceinline__ short f2b(float f) {
    __hip_bfloat16 h = __float2bfloat16(f);
    short s;
    __builtin_memcpy(&s, &h, 2);
    return s;
}
__device__ __forceinline__ float b2f(short s) {
    union { unsigned u; float f; } v; v.u = ((unsigned)(unsigned short)s) << 16;
    return v.f;
}
// swizzled short-index into a [rows][64] bf16 LDS tile (row stride 128B).
__device__ __forceinline__ int swi(int row, int kElem) {
    return (row * 128 + ((kElem * 2) ^ ((row & 7) << 4))) >> 1;
}
__device__ __forceinline__ f32x4 MF(s8v a, s8v b, f32x4 c) {
    return __builtin_amdgcn_mfma_f32_16x16x32_bf16(a, b, c, 0, 0, 0);
}

// ---------------------------------------------------------------------------
// k0: transpose+convert weights.
// ---------------------------------------------------------------------------
__global__ __launch_bounds__(256) void k0(const float* __restrict__ h_w,
                                          const float* __restrict__ a_w,
                                          short* __restrict__ h_wT,
                                          short* __restrict__ a_wT) {
    __shared__ float t[64][68];
    const int tid = threadIdx.x, id = blockIdx.x;
    const float* src; short* dst; int srw, d0, y0;
    if (id < 256) { src = h_w; dst = h_wT; srw = LABh; d0 = (id & 15) * 64; y0 = (id >> 4) * 64; }
    else          { src = a_w; dst = a_wT; srw = OSo;  d0 = (id - 256) * 64; y0 = 0; }
    const int r = tid >> 2, cofs = (tid & 3) * 16;
    #pragma unroll
    for (int w = 0; w < 4; ++w) {
        float4 v = *(const float4*)&src[(size_t)(d0 + r) * srw + y0 + cofs + w * 4];
        t[r][cofs + w * 4 + 0] = v.x;
        t[r][cofs + w * 4 + 1] = v.y;
        t[r][cofs + w * 4 + 2] = v.z;
        t[r][cofs + w * 4 + 3] = v.w;
    }
    __syncthreads();
    s8v o0, o1;
    #pragma unroll
    for (int e = 0; e < 8; ++e) { o0[e] = f2b(t[cofs + e][r]); o1[e] = f2b(t[cofs + 8 + e][r]); }
    *(s8v*)&dst[(size_t)(y0 + r) * Dd + d0 + cofs]     = o0;
    *(s8v*)&dst[(size_t)(y0 + r) * Dd + d0 + cofs + 8] = o1;
}

// ---------------------------------------------------------------------------
// k1: StP[z][b][o][l] = (X@a_w)_partialK.  tile 64(l)x64(o), split-K=2
// (512 each), depth-2 prefetch, dbuf LDS.  grid (32,16,2) = 1024 blocks.
// ---------------------------------------------------------------------------
struct R1 { float4 x[4]; s8v w[2]; };

__global__ __launch_bounds__(256) void k1(const float* __restrict__ X,
                                          const short* __restrict__ a_wT,
                                          float* __restrict__ StP) {
    __shared__ __align__(16) char smem[32768];
    float (*ts)[65] = (float(*)[65])smem;                   // epilogue alias
    const int tid = threadIdx.x;
    const int lane = tid & 63, wave = tid >> 6;
    const int wm = wave >> 1, wn = wave & 1;
    const int b = blockIdx.y, l0 = blockIdx.x * 64;
    const int z = blockIdx.z, kbase = z * 512;
    const float* Xb = X + ((size_t)b * Ll + l0) * Dd;
    const int r = tid >> 2, kofs = (tid & 3) * 16;
    f32x4 acc[2][2] = {};
    R1 bufs[2];
    #pragma unroll
    for (int p = 0; p < 2; ++p) {
        const int k0 = kbase + p * 64;
        #pragma unroll
        for (int w = 0; w < 2; ++w) {
            bufs[p].x[2*w]   = *(const float4*)&Xb[(size_t)r * Dd + k0 + kofs + w * 8];
            bufs[p].x[2*w+1] = *(const float4*)&Xb[(size_t)r * Dd + k0 + kofs + w * 8 + 4];
            bufs[p].w[w]     = *(const s8v*)&a_wT[(size_t)r * Dd + k0 + kofs + w * 8];
        }
    }
    #pragma unroll
    for (int t = 0; t < 8; ++t) {
        short* As = (short*)(smem + (t & 1) * 8192);
        short* Bs = (short*)(smem + 16384 + (t & 1) * 8192);
        #pragma unroll
        for (int w = 0; w < 2; ++w) {
            const float* f0 = (const float*)&bufs[t & 1].x[2*w];
            s8v s;
            s[0]=f2b(f0[0]); s[1]=f2b(f0[1]); s[2]=f2b(f0[2]); s[3]=f2b(f0[3]);
            s[4]=f2b(f0[4]); s[5]=f2b(f0[5]); s[6]=f2b(f0[6]); s[7]=f2b(f0[7]);
            *(s8v*)&As[swi(r, kofs + w * 8)] = s;
            *(s8v*)&Bs[swi(r, kofs + w * 8)] = bufs[t & 1].w[w];
        }
        __syncthreads();
        if (t < 6) {                                        // reload just-staged buf, 2 ahead
            const int k0 = kbase + (t + 2) * 64;
            #pragma unroll
            for (int w = 0; w < 2; ++w) {
                bufs[t & 1].x[2*w]   = *(const float4*)&Xb[(size_t)r * Dd + k0 + kofs + w * 8];
                bufs[t & 1].x[2*w+1] = *(const float4*)&Xb[(size_t)r * Dd + k0 + kofs + w * 8 + 4];
                bufs[t & 1].w[w]     = *(const s8v*)&a_wT[(size_t)r * Dd + k0 + kofs + w * 8];
            }
        }
        #pragma unroll
        for (int kk = 0; kk < 2; ++kk) {
            const int kb = kk * 32 + (lane >> 4) * 8;
            s8v a[2], bb[2];
            #pragma unroll
            for (int i = 0; i < 2; ++i)
                a[i] = *(const s8v*)&As[swi(wm * 32 + i * 16 + (lane & 15), kb)];
            #pragma unroll
            for (int j = 0; j < 2; ++j)
                bb[j] = *(const s8v*)&Bs[swi(wn * 32 + j * 16 + (lane & 15), kb)];
            #pragma unroll
            for (int i = 0; i < 2; ++i)
                #pragma unroll
                for (int j = 0; j < 2; ++j)
                    acc[i][j] = MF(a[i], bb[j], acc[i][j]);
        }
    }
    __syncthreads();                                        // before ts alias writes
    #pragma unroll
    for (int i = 0; i < 2; ++i)
        #pragma unroll
        for (int j = 0; j < 2; ++j)
            #pragma unroll
            for (int rr = 0; rr < 4; ++rr)
                ts[wm * 32 + i * 16 + (lane >> 4) * 4 + rr][wn * 32 + j * 16 + (lane & 15)] = acc[i][j][rr];
    __syncthreads();
    const int o = tid >> 2, lofs = (tid & 3) * 16;
    float* Sp = StP + (size_t)z * ((size_t)Bb * OSo * Ll)
                    + ((size_t)b * OSo + o) * Ll + l0 + lofs;
    #pragma unroll
    for (int w = 0; w < 4; ++w) {
        float4 v;
        v.x = ts[lofs + w * 4 + 0][o];
        v.y = ts[lofs + w * 4 + 1][o];
        v.z = ts[lofs + w * 4 + 2][o];
        v.w = ts[lofs + w * 4 + 3][o];
        *(float4*)&Sp[w * 4] = v;
    }
}

// ---------------------------------------------------------------------------
// k2: sum 2 St partials + a_b, softmax over L, write alpha bf16
// ---------------------------------------------------------------------------
__global__ __launch_bounds__(256) void k2(const float* __restrict__ StP,
                                          const float* __restrict__ a_b,
                                          short* __restrict__ aBf) {
    __shared__ float row[Ll];
    __shared__ float red[8];
    const size_t ZS = (size_t)Bb * OSo * Ll;
    const float* p0 = StP + (size_t)blockIdx.x * Ll;
    const float* p1 = p0 + ZS;
    short* ab = aBf + (size_t)blockIdx.x * Ll;
    const int tid = threadIdx.x;
    const int wave = tid >> 6, lane = tid & 63;
    const float bias = a_b[blockIdx.x & (OSo - 1)];
    float m = -1e30f;
    for (int i = tid; i < Ll; i += 256) {
        float v = p0[i] + p1[i] + bias;
        row[i] = v; m = fmaxf(m, v);
    }
    #pragma unroll
    for (int off = 32; off; off >>= 1) m = fmaxf(m, __shfl_down(m, off));
    if (lane == 0) red[wave] = m;
    __syncthreads();
    if (tid == 0) red[4] = fmaxf(fmaxf(red[0], red[1]), fmaxf(red[2], red[3]));
    __syncthreads();
    const float M = red[4];
    float s = 0.f;
    for (int i = tid; i < Ll; i += 256) { float e = __expf(row[i] - M); row[i] = e; s += e; }
    __syncthreads();
    #pragma unroll
    for (int off = 32; off; off >>= 1) s += __shfl_down(s, off);
    if (lane == 0) red[wave] = s;
    __syncthreads();
    if (tid == 0) red[4] = 1.f / (red[0] + red[1] + red[2] + red[3]);
    __syncthreads();
    const float inv = red[4];
    for (int i = tid; i < Ll; i += 256) ab[i] = f2b(row[i] * inv);
}

// ---------------------------------------------------------------------------
// k3: Xp_part[z] = alpha_quarter @ X_quarter.  tile 64(o)x64(d), split-K=4
// (512 l each), depth-2 prefetch, dbuf LDS.  1024 blocks, XCD-grouped by b.
// X transposed 4x4 in regs with bank-uniform store map.
// ---------------------------------------------------------------------------
struct R3 { s8v al[2]; float4 xv[4]; };

__global__ __launch_bounds__(256) void k3(const float* __restrict__ X,
                                          const short* __restrict__ aBf,
                                          float* __restrict__ XpP) {
    __shared__ __align__(16) char smem[32768];
    float (*ts)[68] = (float(*)[68])smem;                   // epilogue alias
    const int tid = threadIdx.x;
    const int lane = tid & 63, wave = tid >> 6;
    const int wm = wave >> 1, wn = wave & 1;
    const int id = blockIdx.x;
    const int slot = id >> 3;
    const int b = (id & 7) * 2 + (slot >> 6);               // same-b -> same XCD
    const int inner = slot & 63;
    const int dt = inner & 15, z = inner >> 4;              // z in 0..3
    const int d0 = dt * 64;
    const float* Xb = X + (size_t)b * Ll * Dd;
    const short* ab = aBf + (size_t)b * OSo * Ll;
    float* outP = XpP + (size_t)z * ((size_t)Bb * OSo * Dd);
    f32x4 acc[2][2] = {};
    const int arow = tid >> 2, akofs = (tid & 3) * 16;
    const int lq = tid & 15, dq = tid >> 4;
    const int lbase = z * 512;
    R3 bufs[2];
    #pragma unroll
    for (int p = 0; p < 2; ++p) {
        const int l0 = lbase + p * 64;
        #pragma unroll
        for (int w = 0; w < 2; ++w)
            bufs[p].al[w] = *(const s8v*)&ab[(size_t)arow * Ll + l0 + akofs + w * 8];
        #pragma unroll
        for (int i = 0; i < 4; ++i)
            bufs[p].xv[i] = *(const float4*)&Xb[(size_t)(l0 + lq * 4 + i) * Dd + d0 + dq * 4];
    }
    #pragma unroll
    for (int t = 0; t < 8; ++t) {
        short* Aal = (short*)(smem + (t & 1) * 8192);
        short* Xs  = (short*)(smem + 16384 + (t & 1) * 8192);
        #pragma unroll
        for (int w = 0; w < 2; ++w)
            *(s8v*)&Aal[swi(arow, akofs + w * 8)] = bufs[t & 1].al[w];
        {
            const float* f = (const float*)bufs[t & 1].xv;  // f[i*4+j] = X[l=lq*4+i][d=dq*4+j]
            #pragma unroll
            for (int j = 0; j < 4; ++j) {
                const int rowd = dq * 4 + j;
                s4v sj;
                sj[0] = f2b(f[0 * 4 + j]);
                sj[1] = f2b(f[1 * 4 + j]);
                sj[2] = f2b(f[2 * 4 + j]);
                sj[3] = f2b(f[3 * 4 + j]);
                *(s4v*)&Xs[swi(rowd, lq * 4)] = sj;
            }
        }
        __syncthreads();
        if (t < 6) {                                        // reload just-staged buf, 2 ahead
            const int l0 = lbase + (t + 2) * 64;
            #pragma unroll
            for (int w = 0; w < 2; ++w)
                bufs[t & 1].al[w] = *(const s8v*)&ab[(size_t)arow * Ll + l0 + akofs + w * 8];
            #pragma unroll
            for (int i = 0; i < 4; ++i)
                bufs[t & 1].xv[i] = *(const float4*)&Xb[(size_t)(l0 + lq * 4 + i) * Dd + d0 + dq * 4];
        }
        #pragma unroll
        for (int kk = 0; kk < 2; ++kk) {
            const int kb = kk * 32 + (lane >> 4) * 8;
            s8v a[2], bb[2];
            #pragma unroll
            for (int i = 0; i < 2; ++i)
                a[i] = *(const s8v*)&Aal[swi(wm * 32 + i * 16 + (lane & 15), kb)];
            #pragma unroll
            for (int j = 0; j < 2; ++j)
                bb[j] = *(const s8v*)&Xs[swi(wn * 32 + j * 16 + (lane & 15), kb)];
            #pragma unroll
            for (int i = 0; i < 2; ++i)
                #pragma unroll
                for (int j = 0; j < 2; ++j)
                    acc[i][j] = MF(a[i], bb[j], acc[i][j]);
        }
    }
    __syncthreads();
    #pragma unroll
    for (int i = 0; i < 2; ++i)
        #pragma unroll
        for (int j = 0; j < 2; ++j)
            #pragma unroll
            for (int rr = 0; rr < 4; ++rr)
                ts[wm * 32 + i * 16 + (lane >> 4) * 4 + rr][wn * 32 + j * 16 + (lane & 15)] = acc[i][j][rr];
    __syncthreads();
    const int o = tid >> 2, dofs = (tid & 3) * 16;
    float* op = outP + ((size_t)b * OSo + o) * Dd + d0 + dofs;
    #pragma unroll
    for (int w = 0; w < 4; ++w)
        *(float4*)&op[w * 4] = *(float4*)&ts[o][dofs + w * 4];
}

// ---------------------------------------------------------------------------
// k4: Xh = bf16(relu(BN((sum_z XpP[z])@h_w + h_b)))  tile 64x64, dbuf+prefetch
// 4-partial split-K reduce fused into the A-operand staging.
// ---------------------------------------------------------------------------
struct R4 { float4 p[16]; s8v w[2]; };

__global__ __launch_bounds__(256) void k4(const float* __restrict__ XpP,
                                          const short* __restrict__ h_wT,
                                          const float* __restrict__ h_b,
                                          const float* __restrict__ gamma,
                                          const float* __restrict__ beta,
                                          const float* __restrict__ mean,
                                          const float* __restrict__ var,
                                          short* __restrict__ Xh) {
    __shared__ __align__(16) char smem[32768];
    short* tsb = (short*)smem;                              // epilogue alias [64][64]
    const int tid = threadIdx.x, lane = tid & 63, wave = tid >> 6;
    const int wm = wave >> 1, wn = wave & 1;
    const int h0 = blockIdx.x * 64, m0 = blockIdx.y * 64;
    const int r = tid >> 2, kofs = (tid & 3) * 16;
    const size_t ZS = (size_t)Bb * OSo * Dd;
    f32x4 acc[2][2] = {};
    R4 cur, nxt;
    #pragma unroll
    for (int w = 0; w < 2; ++w) {
        const float* p0 = XpP + (size_t)(m0 + r) * Dd + kofs + w * 8;
        #pragma unroll
        for (int zz = 0; zz < 4; ++zz) {
            cur.p[w*8 + zz*2]     = *(const float4*)&p0[zz * ZS];
            cur.p[w*8 + zz*2 + 1] = *(const float4*)&p0[zz * ZS + 4];
        }
        cur.w[w] = *(const s8v*)&h_wT[(size_t)(h0 + r) * Dd + kofs + w * 8];
    }
    #pragma unroll
    for (int t = 0; t < 16; ++t) {
        short* As = (short*)(smem + (t & 1) * 8192);
        short* Bs = (short*)(smem + 16384 + (t & 1) * 8192);
        #pragma unroll
        for (int w = 0; w < 2; ++w) {
            const float* f0 = (const float*)&cur.p[w*8];        // z0: 8 f32
            const float* f1 = (const float*)&cur.p[w*8 + 2];    // z1
            const float* f2 = (const float*)&cur.p[w*8 + 4];    // z2
            const float* f3 = (const float*)&cur.p[w*8 + 6];    // z3
            s8v s;
            #pragma unroll
            for (int e = 0; e < 8; ++e) s[e] = f2b((f0[e] + f1[e]) + (f2[e] + f3[e]));
            *(s8v*)&As[swi(r, kofs + w * 8)] = s;
            *(s8v*)&Bs[swi(r, kofs + w * 8)] = cur.w[w];
        }
        __syncthreads();
        if (t < 15) {
            const int k0 = (t + 1) * 64;
            #pragma unroll
            for (int w = 0; w < 2; ++w) {
                const float* p0 = XpP + (size_t)(m0 + r) * Dd + k0 + kofs + w * 8;
                #pragma unroll
                for (int zz = 0; zz < 4; ++zz) {
                    nxt.p[w*8 + zz*2]     = *(const float4*)&p0[zz * ZS];
                    nxt.p[w*8 + zz*2 + 1] = *(const float4*)&p0[zz * ZS + 4];
                }
                nxt.w[w] = *(const s8v*)&h_wT[(size_t)(h0 + r) * Dd + k0 + kofs + w * 8];
            }
        }
        #pragma unroll
        for (int kk = 0; kk < 2; ++kk) {
            const int kb = kk * 32 + (lane >> 4) * 8;
            s8v a[2], bb[2];
            #pragma unroll
            for (int i = 0; i < 2; ++i)
                a[i] = *(const s8v*)&As[swi(wm * 32 + i * 16 + (lane & 15), kb)];
            #pragma unroll
            for (int j = 0; j < 2; ++j)
                bb[j] = *(const s8v*)&Bs[swi(wn * 32 + j * 16 + (lane & 15), kb)];
            #pragma unroll
            for (int i = 0; i < 2; ++i)
                #pragma unroll
                for (int j = 0; j < 2; ++j)
                    acc[i][j] = MF(a[i], bb[j], acc[i][j]);
        }
        if (t < 15) cur = nxt;
    }
    __syncthreads();
    #pragma unroll
    for (int j = 0; j < 2; ++j) {
        const int h = h0 + wn * 32 + j * 16 + (lane & 15);
        const float sc = gamma[h] * rsqrtf(var[h] + BN_EPS);
        const float of = (h_b[h] - mean[h]) * sc + beta[h];
        #pragma unroll
        for (int i = 0; i < 2; ++i)
            #pragma unroll
            for (int rr = 0; rr < 4; ++rr) {
                const int ml = wm * 32 + i * 16 + (lane >> 4) * 4 + rr;
                tsb[ml * 64 + wn * 32 + j * 16 + (lane & 15)] = f2b(fmaxf(0.f, acc[i][j][rr] * sc + of));
            }
    }
    __syncthreads();
    #pragma unroll
    for (int w = 0; w < 2; ++w)
        *(s8v*)&Xh[(size_t)(m0 + r) * LABh + h0 + kofs + w * 8] = *(const s8v*)&tsb[r * 64 + kofs + w * 8];
}

// ---------------------------------------------------------------------------
// k5: scP[z][b][c][o] partial over K range z.  tile 64(c)x64(o), split-K=4,
// dbuf+prefetch.  grid (16, 16): x = ct(0..3) + 4*z(0..3).
// ---------------------------------------------------------------------------
struct R5 { float4 ld[4]; s8v xh[2]; };

__global__ __launch_bounds__(256) void k5(const int* __restrict__ cand,
                                          const float* __restrict__ labD,
                                          const short* __restrict__ Xh,
                                          float* __restrict__ scP) {
    __shared__ __align__(16) char smem[33024];
    float (*ts)[68] = (float(*)[68])smem;
    int* cidx = (int*)(smem + 32768);
    const int tid = threadIdx.x, lane = tid & 63, wave = tid >> 6;
    const int wm = wave >> 1, wn = wave & 1;
    const int b = blockIdx.y;
    const int ct = blockIdx.x & 3, z = blockIdx.x >> 2;
    const int c0 = ct * 64;
    const int kbase = z * 256;
    if (tid < 64) cidx[tid] = cand[b * NCc + c0 + tid];
    __syncthreads();
    const int r = tid >> 2, kofs = (tid & 3) * 16;
    const int ci = cidx[r];
    const float* lrow = labD + (size_t)ci * LABh + kbase;
    const short* xrow = Xh + (size_t)(b * OSo + r) * LABh + kbase;
    f32x4 acc[2][2] = {};
    R5 cur, nxt;
    #pragma unroll
    for (int w = 0; w < 2; ++w) {
        cur.ld[2*w]   = *(const float4*)&lrow[kofs + w * 8];
        cur.ld[2*w+1] = *(const float4*)&lrow[kofs + w * 8 + 4];
        cur.xh[w]     = *(const s8v*)&xrow[kofs + w * 8];
    }
    #pragma unroll
    for (int t = 0; t < 4; ++t) {
        short* As = (short*)(smem + (t & 1) * 8192);
        short* Bs = (short*)(smem + 16384 + (t & 1) * 8192);
        #pragma unroll
        for (int w = 0; w < 2; ++w) {
            const float* f0 = (const float*)&cur.ld[2*w];
            s8v s;
            #pragma unroll
            for (int e = 0; e < 8; ++e) s[e] = f2b(f0[e]);
            *(s8v*)&As[swi(r, kofs + w * 8)] = s;
            *(s8v*)&Bs[swi(r, kofs + w * 8)] = cur.xh[w];
        }
        __syncthreads();
        if (t < 3) {
            const int k0 = (t + 1) * 64;
            #pragma unroll
            for (int w = 0; w < 2; ++w) {
                nxt.ld[2*w]   = *(const float4*)&lrow[k0 + kofs + w * 8];
                nxt.ld[2*w+1] = *(const float4*)&lrow[k0 + kofs + w * 8 + 4];
                nxt.xh[w]     = *(const s8v*)&xrow[k0 + kofs + w * 8];
            }
        }
        #pragma unroll
        for (int kk = 0; kk < 2; ++kk) {
            const int kb = kk * 32 + (lane >> 4) * 8;
            s8v a[2], bb[2];
            #pragma unroll
            for (int i = 0; i < 2; ++i)
                a[i] = *(const s8v*)&As[swi(wm * 32 + i * 16 + (lane & 15), kb)];
            #pragma unroll
            for (int j = 0; j < 2; ++j)
                bb[j] = *(const s8v*)&Bs[swi(wn * 32 + j * 16 + (lane & 15), kb)];
            #pragma unroll
            for (int i = 0; i < 2; ++i)
                #pragma unroll
                for (int j = 0; j < 2; ++j)
                    acc[i][j] = MF(a[i], bb[j], acc[i][j]);
        }
        if (t < 3) cur = nxt;
    }
    __syncthreads();
    #pragma unroll
    for (int i = 0; i < 2; ++i)
        #pragma unroll
        for (int j = 0; j < 2; ++j)
            #pragma unroll
            for (int rr = 0; rr < 4; ++rr)
                ts[wm * 32 + i * 16 + (lane >> 4) * 4 + rr][wn * 32 + j * 16 + (lane & 15)] = acc[i][j][rr];
    __syncthreads();
    const int oofs = (tid & 3) * 16;
    float* sp = scP + (size_t)z * ((size_t)Bb * NCc * OSo)
                    + ((size_t)b * NCc + c0 + r) * OSo + oofs;
    #pragma unroll
    for (int w = 0; w < 4; ++w)
        *(float4*)&sp[w * 4] = *(float4*)&ts[r][oofs + w * 4];
}

// ---------------------------------------------------------------------------
// k6: sum split-K partials of sc, softmax over o, out = alpha2^T @ Xh
// 512 blocks (8-candidate tiles), XCD-grouped by b.
// ---------------------------------------------------------------------------
__global__ __launch_bounds__(256) void k6(const float* __restrict__ scP,
                                          const short* __restrict__ Xh,
                                          float* __restrict__ out) {
    __shared__ float al[8][64];
    const int tid = threadIdx.x;
    const int id = blockIdx.x;
    const int slot = id >> 3;
    const int b = (id & 7) * 2 + (slot >> 5);
    const int c0 = (slot & 31) * 8;
    const size_t ZS = (size_t)Bb * NCc * OSo;
    {
        const int cl = tid >> 5, t32 = tid & 31;
        const float* srow = scP + ((size_t)b * NCc + c0 + cl) * OSo;
        float v[2];
        float m = -1e30f;
        #pragma unroll
        for (int j = 0; j < 2; ++j) {
            const int o = t32 + j * 32;
            v[j] = srow[o] + srow[ZS + o] + srow[2 * ZS + o] + srow[3 * ZS + o];
            m = fmaxf(m, v[j]);
        }
        #pragma unroll
        for (int off = 16; off; off >>= 1) m = fmaxf(m, __shfl_xor(m, off, 32));
        float s = 0.f;
        #pragma unroll
        for (int j = 0; j < 2; ++j) { v[j] = __expf(v[j] - m); s += v[j]; }
        #pragma unroll
        for (int off = 16; off; off >>= 1) s += __shfl_xor(s, off, 32);
        float inv = 1.f / s;
        #pragma unroll
        for (int j = 0; j < 2; ++j) al[cl][t32 + j * 32] = v[j] * inv;
    }
    __syncthreads();
    const short* xb = Xh + (size_t)b * OSo * LABh;
    float acc[8][4] = {};
    for (int o = 0; o < OSo; ++o) {
        s4v xv = *(const s4v*)&xb[(size_t)o * LABh + tid * 4];
        const float x0 = b2f(xv[0]), x1 = b2f(xv[1]), x2 = b2f(xv[2]), x3 = b2f(xv[3]);
        #pragma unroll
        for (int c = 0; c < 8; ++c) {
            const float w = al[c][o];
            acc[c][0] += w * x0; acc[c][1] += w * x1; acc[c][2] += w * x2; acc[c][3] += w * x3;
        }
    }
    #pragma unroll
    for (int c = 0; c < 8; ++c) {
        float4 v; v.x = acc[c][0]; v.y = acc[c][1]; v.z = acc[c][2]; v.w = acc[c][3];
        *(float4*)&out[((size_t)b * NCc + c0 + c) * LABh + tid * 4] = v;
    }
}

// ---------------------------------------------------------------------------
extern "C" void kernel_launch(void* const* d_in, const int* in_sizes, int n_in,
                              void* d_out, int out_size, void* d_ws, size_t ws_size,
                              hipStream_t stream) {
    (void)in_sizes; (void)n_in; (void)out_size; (void)ws_size;
    const float* X      = (const float*)d_in[0];
    const int*   cand   = (const int*)  d_in[1];
    const float* a_w    = (const float*)d_in[2];
    const float* a_b    = (const float*)d_in[3];
    const float* h_w    = (const float*)d_in[4];
    const float* h_b    = (const float*)d_in[5];
    const float* gamma  = (const float*)d_in[6];
    const float* beta   = (const float*)d_in[7];
    const float* mean   = (const float*)d_in[8];
    const float* var    = (const float*)d_in[9];
    const float* labDesc= (const float*)d_in[10];
    float* outp = (float*)d_out;

    char* ws = (char*)d_ws;
    float* StP  = (float*)ws;                               // 16MB (2 partials); XpP aliases after k2
    float* XpP  = (float*)ws;                               // 16MB (4 partials)
    short* aBf  = (short*)(ws + ((size_t)16 << 20));        // 4MB alpha bf16
    short* Xh   = (short*)(ws + ((size_t)20 << 20));        // 2MB
    float* scP  = (float*)(ws + ((size_t)22 << 20));        // 4MB (4 split-K partials)
    short* a_wT = (short*)(ws + ((size_t)26 << 20));        // 128KB
    short* h_wT = (short*)(ws + ((size_t)27 << 20));        // 2MB

    k0 <<<272,              256, 0, stream>>>(h_w, a_w, h_wT, a_wT);
    k1 <<<dim3(32, 16, 2),  256, 0, stream>>>(X, a_wT, StP);
    k2 <<<Bb * OSo,         256, 0, stream>>>(StP, a_b, aBf);
    k3 <<<1024,             256, 0, stream>>>(X, aBf, XpP);
    k4 <<<dim3(16, 16),     256, 0, stream>>>(XpP, h_wT, h_b, gamma, beta, mean, var, Xh);
    k5 <<<dim3(16, 16),     256, 0, stream>>>(cand, labDesc, Xh, scP);
    k6 <<<512,              256, 0, stream>>>(scP, Xh, outp);
}

// Round 8
// 110.934 us; speedup vs baseline: 1.1486x; 1.1486x over previous
//
#include <hip/hip_runtime.h>
#include <hip/hip_bf16.h>
#include <math.h>

#define Bb   16
#define Ll   2048
#define Dd   1024
#define OSo  64
#define NCc  256
#define LABh 1024
#define BN_EPS 1e-5f

typedef short s8v  __attribute__((ext_vector_type(8)));   // 8 bf16 = 4 VGPR
typedef short s4v  __attribute__((ext_vector_type(4)));
typedef float f32x4 __attribute__((ext_vector_type(4)));

__device__ __forceinline__ short f2b(float f) {
    __hip_bfloat16 h = __float2bfloat16(f);
    short s;
    __builtin_memcpy(&s, &h, 2);
    return s;
}
__device__ __forceinline__ float b2f(short s) {
    union { unsigned u; float f; } v; v.u = ((unsigned)(unsigned short)s) << 16;
    return v.f;
}
// Barrier WITHOUT the vmcnt(0) drain: waits only for this wave's LDS ops,
// leaving prefetch global-loads in flight across the barrier (T4).
__device__ __forceinline__ void fastbar() {
    asm volatile("s_waitcnt lgkmcnt(0)\n\ts_barrier" ::: "memory");
}
// swizzled short-index into a [rows][64] bf16 LDS tile (row stride 128B).
__device__ __forceinline__ int swi(int row, int kElem) {
    return (row * 128 + ((kElem * 2) ^ ((row & 7) << 4))) >> 1;
}
__device__ __forceinline__ f32x4 MF(s8v a, s8v b, f32x4 c) {
    return __builtin_amdgcn_mfma_f32_16x16x32_bf16(a, b, c, 0, 0, 0);
}

// ---------------------------------------------------------------------------
// k0: transpose+convert weights.
// ---------------------------------------------------------------------------
__global__ __launch_bounds__(256) void k0(const float* __restrict__ h_w,
                                          const float* __restrict__ a_w,
                                          short* __restrict__ h_wT,
                                          short* __restrict__ a_wT) {
    __shared__ float t[64][68];
    const int tid = threadIdx.x, id = blockIdx.x;
    const float* src; short* dst; int srw, d0, y0;
    if (id < 256) { src = h_w; dst = h_wT; srw = LABh; d0 = (id & 15) * 64; y0 = (id >> 4) * 64; }
    else          { src = a_w; dst = a_wT; srw = OSo;  d0 = (id - 256) * 64; y0 = 0; }
    const int r = tid >> 2, cofs = (tid & 3) * 16;
    #pragma unroll
    for (int w = 0; w < 4; ++w) {
        float4 v = *(const float4*)&src[(size_t)(d0 + r) * srw + y0 + cofs + w * 4];
        t[r][cofs + w * 4 + 0] = v.x;
        t[r][cofs + w * 4 + 1] = v.y;
        t[r][cofs + w * 4 + 2] = v.z;
        t[r][cofs + w * 4 + 3] = v.w;
    }
    __syncthreads();
    s8v o0, o1;
    #pragma unroll
    for (int e = 0; e < 8; ++e) { o0[e] = f2b(t[cofs + e][r]); o1[e] = f2b(t[cofs + 8 + e][r]); }
    *(s8v*)&dst[(size_t)(y0 + r) * Dd + d0 + cofs]     = o0;
    *(s8v*)&dst[(size_t)(y0 + r) * Dd + d0 + cofs + 8] = o1;
}

// ---------------------------------------------------------------------------
// k1: St[b][o][l] = X@a_w + a_b.  tile 64(l)x64(o), K=1024, dbuf+prefetch.
// ---------------------------------------------------------------------------
struct R1 { float4 x[4]; s8v w[2]; };

__global__ __launch_bounds__(256) void k1(const float* __restrict__ X,
                                          const short* __restrict__ a_wT,
                                          const float* __restrict__ a_b,
                                          float* __restrict__ St) {
    __shared__ __align__(16) char smem[32768];
    float (*ts)[65] = (float(*)[65])smem;                   // epilogue alias
    const int tid = threadIdx.x;
    const int lane = tid & 63, wave = tid >> 6;
    const int wm = wave >> 1, wn = wave & 1;
    const int b = blockIdx.y, l0 = blockIdx.x * 64;
    const float* Xb = X + ((size_t)b * Ll + l0) * Dd;
    const int r = tid >> 2, kofs = (tid & 3) * 16;
    f32x4 acc[2][2] = {};
    R1 cur, nxt;
    #pragma unroll
    for (int w = 0; w < 2; ++w) {
        cur.x[2*w]   = *(const float4*)&Xb[(size_t)r * Dd + kofs + w * 8];
        cur.x[2*w+1] = *(const float4*)&Xb[(size_t)r * Dd + kofs + w * 8 + 4];
        cur.w[w]     = *(const s8v*)&a_wT[(size_t)r * Dd + kofs + w * 8];
    }
    #pragma unroll
    for (int t = 0; t < 16; ++t) {
        short* As = (short*)(smem + (t & 1) * 8192);
        short* Bs = (short*)(smem + 16384 + (t & 1) * 8192);
        #pragma unroll
        for (int w = 0; w < 2; ++w) {
            const float* f0 = (const float*)&cur.x[2*w];
            s8v s;
            s[0]=f2b(f0[0]); s[1]=f2b(f0[1]); s[2]=f2b(f0[2]); s[3]=f2b(f0[3]);
            s[4]=f2b(f0[4]); s[5]=f2b(f0[5]); s[6]=f2b(f0[6]); s[7]=f2b(f0[7]);
            *(s8v*)&As[swi(r, kofs + w * 8)] = s;
            *(s8v*)&Bs[swi(r, kofs + w * 8)] = cur.w[w];
        }
        fastbar();
        if (t < 15) {
            const int k0 = (t + 1) * 64;
            #pragma unroll
            for (int w = 0; w < 2; ++w) {
                nxt.x[2*w]   = *(const float4*)&Xb[(size_t)r * Dd + k0 + kofs + w * 8];
                nxt.x[2*w+1] = *(const float4*)&Xb[(size_t)r * Dd + k0 + kofs + w * 8 + 4];
                nxt.w[w]     = *(const s8v*)&a_wT[(size_t)r * Dd + k0 + kofs + w * 8];
            }
        }
        #pragma unroll
        for (int kk = 0; kk < 2; ++kk) {
            const int kb = kk * 32 + (lane >> 4) * 8;
            s8v a[2], bb[2];
            #pragma unroll
            for (int i = 0; i < 2; ++i)
                a[i] = *(const s8v*)&As[swi(wm * 32 + i * 16 + (lane & 15), kb)];
            #pragma unroll
            for (int j = 0; j < 2; ++j)
                bb[j] = *(const s8v*)&Bs[swi(wn * 32 + j * 16 + (lane & 15), kb)];
            #pragma unroll
            for (int i = 0; i < 2; ++i)
                #pragma unroll
                for (int j = 0; j < 2; ++j)
                    acc[i][j] = MF(a[i], bb[j], acc[i][j]);
        }
        if (t < 15) cur = nxt;
    }
    __syncthreads();                                        // before ts alias writes
    #pragma unroll
    for (int i = 0; i < 2; ++i)
        #pragma unroll
        for (int j = 0; j < 2; ++j)
            #pragma unroll
            for (int rr = 0; rr < 4; ++rr)
                ts[wm * 32 + i * 16 + (lane >> 4) * 4 + rr][wn * 32 + j * 16 + (lane & 15)] = acc[i][j][rr];
    __syncthreads();
    const int o = tid >> 2, lofs = (tid & 3) * 16;
    const float bias = a_b[o];
    float* Sp = St + ((size_t)b * OSo + o) * Ll + l0 + lofs;
    #pragma unroll
    for (int w = 0; w < 4; ++w) {
        float4 v;
        v.x = ts[lofs + w * 4 + 0][o] + bias;
        v.y = ts[lofs + w * 4 + 1][o] + bias;
        v.z = ts[lofs + w * 4 + 2][o] + bias;
        v.w = ts[lofs + w * 4 + 3][o] + bias;
        *(float4*)&Sp[w * 4] = v;
    }
}

// ---------------------------------------------------------------------------
// k2: softmax over L per (b,o) row; St f32 in -> alpha bf16 out
// ---------------------------------------------------------------------------
__global__ __launch_bounds__(256) void k2(const float* __restrict__ St, short* __restrict__ aBf) {
    __shared__ float row[Ll];
    __shared__ float red[8];
    const float* p = St + (size_t)blockIdx.x * Ll;
    short* ab = aBf + (size_t)blockIdx.x * Ll;
    const int tid = threadIdx.x;
    const int wave = tid >> 6, lane = tid & 63;
    float m = -1e30f;
    for (int i = tid; i < Ll; i += 256) { float v = p[i]; row[i] = v; m = fmaxf(m, v); }
    #pragma unroll
    for (int off = 32; off; off >>= 1) m = fmaxf(m, __shfl_down(m, off));
    if (lane == 0) red[wave] = m;
    __syncthreads();
    if (tid == 0) red[4] = fmaxf(fmaxf(red[0], red[1]), fmaxf(red[2], red[3]));
    __syncthreads();
    const float M = red[4];
    float s = 0.f;
    for (int i = tid; i < Ll; i += 256) { float e = __expf(row[i] - M); row[i] = e; s += e; }
    __syncthreads();
    #pragma unroll
    for (int off = 32; off; off >>= 1) s += __shfl_down(s, off);
    if (lane == 0) red[wave] = s;
    __syncthreads();
    if (tid == 0) red[4] = 1.f / (red[0] + red[1] + red[2] + red[3]);
    __syncthreads();
    const float inv = red[4];
    for (int i = tid; i < Ll; i += 256) ab[i] = f2b(row[i] * inv);
}

// ---------------------------------------------------------------------------
// k3: Xp_part[z] = alpha_half @ X_half.  tile 64(o)x64(d), split-K=2,
// dbuf+prefetch; X transposed 4x4 in regs with bank-uniform store map.
// ---------------------------------------------------------------------------
struct R3 { s8v al[2]; float4 xv[4]; };

__global__ __launch_bounds__(256) void k3(const float* __restrict__ X,
                                          const short* __restrict__ aBf,
                                          float* __restrict__ XpP) {
    __shared__ __align__(16) char smem[32768];
    float (*ts)[68] = (float(*)[68])smem;                   // epilogue alias
    const int tid = threadIdx.x;
    const int lane = tid & 63, wave = tid >> 6;
    const int wm = wave >> 1, wn = wave & 1;
    const int id = blockIdx.x;
    const int slot = id >> 3;
    const int b = (id & 7) * 2 + (slot >> 5);
    const int inner = slot & 31;
    const int dt = inner & 15, z = inner >> 4;
    const int d0 = dt * 64;
    const float* Xb = X + (size_t)b * Ll * Dd;
    const short* ab = aBf + (size_t)b * OSo * Ll;
    float* outP = XpP + (size_t)z * ((size_t)Bb * OSo * Dd);
    f32x4 acc[2][2] = {};
    const int arow = tid >> 2, akofs = (tid & 3) * 16;
    const int lq = tid & 15, dq = tid >> 4;
    const int lbase = z * 1024;
    R3 cur, nxt;
    #pragma unroll
    for (int w = 0; w < 2; ++w)
        cur.al[w] = *(const s8v*)&ab[(size_t)arow * Ll + lbase + akofs + w * 8];
    #pragma unroll
    for (int i = 0; i < 4; ++i)
        cur.xv[i] = *(const float4*)&Xb[(size_t)(lbase + lq * 4 + i) * Dd + d0 + dq * 4];
    #pragma unroll
    for (int t = 0; t < 16; ++t) {
        short* Aal = (short*)(smem + (t & 1) * 8192);
        short* Xs  = (short*)(smem + 16384 + (t & 1) * 8192);
        #pragma unroll
        for (int w = 0; w < 2; ++w)
            *(s8v*)&Aal[swi(arow, akofs + w * 8)] = cur.al[w];
        {
            const float* f = (const float*)cur.xv;          // f[i*4+j] = X[l=lq*4+i][d=dq*4+j]
            #pragma unroll
            for (int j = 0; j < 4; ++j) {
                const int rowd = dq * 4 + j;
                s4v sj;
                sj[0] = f2b(f[0 * 4 + j]);
                sj[1] = f2b(f[1 * 4 + j]);
                sj[2] = f2b(f[2 * 4 + j]);
                sj[3] = f2b(f[3 * 4 + j]);
                *(s4v*)&Xs[swi(rowd, lq * 4)] = sj;
            }
        }
        fastbar();
        if (t < 15) {
            const int l0 = lbase + (t + 1) * 64;
            #pragma unroll
            for (int w = 0; w < 2; ++w)
                nxt.al[w] = *(const s8v*)&ab[(size_t)arow * Ll + l0 + akofs + w * 8];
            #pragma unroll
            for (int i = 0; i < 4; ++i)
                nxt.xv[i] = *(const float4*)&Xb[(size_t)(l0 + lq * 4 + i) * Dd + d0 + dq * 4];
        }
        #pragma unroll
        for (int kk = 0; kk < 2; ++kk) {
            const int kb = kk * 32 + (lane >> 4) * 8;
            s8v a[2], bb[2];
            #pragma unroll
            for (int i = 0; i < 2; ++i)
                a[i] = *(const s8v*)&Aal[swi(wm * 32 + i * 16 + (lane & 15), kb)];
            #pragma unroll
            for (int j = 0; j < 2; ++j)
                bb[j] = *(const s8v*)&Xs[swi(wn * 32 + j * 16 + (lane & 15), kb)];
            #pragma unroll
            for (int i = 0; i < 2; ++i)
                #pragma unroll
                for (int j = 0; j < 2; ++j)
                    acc[i][j] = MF(a[i], bb[j], acc[i][j]);
        }
        if (t < 15) cur = nxt;
    }
    __syncthreads();
    #pragma unroll
    for (int i = 0; i < 2; ++i)
        #pragma unroll
        for (int j = 0; j < 2; ++j)
            #pragma unroll
            for (int rr = 0; rr < 4; ++rr)
                ts[wm * 32 + i * 16 + (lane >> 4) * 4 + rr][wn * 32 + j * 16 + (lane & 15)] = acc[i][j][rr];
    __syncthreads();
    const int o = tid >> 2, dofs = (tid & 3) * 16;
    float* op = outP + ((size_t)b * OSo + o) * Dd + d0 + dofs;
    #pragma unroll
    for (int w = 0; w < 4; ++w)
        *(float4*)&op[w * 4] = *(float4*)&ts[o][dofs + w * 4];
}

// ---------------------------------------------------------------------------
// k4: Xh = bf16(relu(BN((XpP0+XpP1)@h_w + h_b)))  tile 64x64, dbuf+prefetch
// ---------------------------------------------------------------------------
struct R4 { float4 p[8]; s8v w[2]; };

__global__ __launch_bounds__(256) void k4(const float* __restrict__ XpP,
                                          const short* __restrict__ h_wT,
                                          const float* __restrict__ h_b,
                                          const float* __restrict__ gamma,
                                          const float* __restrict__ beta,
                                          const float* __restrict__ mean,
                                          const float* __restrict__ var,
                                          short* __restrict__ Xh) {
    __shared__ __align__(16) char smem[32768];
    short* tsb = (short*)smem;                              // epilogue alias [64][64]
    const int tid = threadIdx.x, lane = tid & 63, wave = tid >> 6;
    const int wm = wave >> 1, wn = wave & 1;
    const int h0 = blockIdx.x * 64, m0 = blockIdx.y * 64;
    const int r = tid >> 2, kofs = (tid & 3) * 16;
    const size_t ZS = (size_t)Bb * OSo * Dd;
    f32x4 acc[2][2] = {};
    R4 cur, nxt;
    #pragma unroll
    for (int w = 0; w < 2; ++w) {
        const float* p0 = XpP + (size_t)(m0 + r) * Dd + kofs + w * 8;
        cur.p[w*4+0] = *(const float4*)&p0[0];
        cur.p[w*4+1] = *(const float4*)&p0[4];
        cur.p[w*4+2] = *(const float4*)&p0[ZS];
        cur.p[w*4+3] = *(const float4*)&p0[ZS + 4];
        cur.w[w]     = *(const s8v*)&h_wT[(size_t)(h0 + r) * Dd + kofs + w * 8];
    }
    #pragma unroll
    for (int t = 0; t < 16; ++t) {
        short* As = (short*)(smem + (t & 1) * 8192);
        short* Bs = (short*)(smem + 16384 + (t & 1) * 8192);
        #pragma unroll
        for (int w = 0; w < 2; ++w) {
            const float* f0 = (const float*)&cur.p[w*4];
            const float* f1 = (const float*)&cur.p[w*4+2];
            s8v s;
            #pragma unroll
            for (int e = 0; e < 8; ++e) s[e] = f2b(f0[e] + f1[e]);
            *(s8v*)&As[swi(r, kofs + w * 8)] = s;
            *(s8v*)&Bs[swi(r, kofs + w * 8)] = cur.w[w];
        }
        fastbar();
        if (t < 15) {
            const int k0 = (t + 1) * 64;
            #pragma unroll
            for (int w = 0; w < 2; ++w) {
                const float* p0 = XpP + (size_t)(m0 + r) * Dd + k0 + kofs + w * 8;
                nxt.p[w*4+0] = *(const float4*)&p0[0];
                nxt.p[w*4+1] = *(const float4*)&p0[4];
                nxt.p[w*4+2] = *(const float4*)&p0[ZS];
                nxt.p[w*4+3] = *(const float4*)&p0[ZS + 4];
                nxt.w[w]     = *(const s8v*)&h_wT[(size_t)(h0 + r) * Dd + k0 + kofs + w * 8];
            }
        }
        #pragma unroll
        for (int kk = 0; kk < 2; ++kk) {
            const int kb = kk * 32 + (lane >> 4) * 8;
            s8v a[2], bb[2];
            #pragma unroll
            for (int i = 0; i < 2; ++i)
                a[i] = *(const s8v*)&As[swi(wm * 32 + i * 16 + (lane & 15), kb)];
            #pragma unroll
            for (int j = 0; j < 2; ++j)
                bb[j] = *(const s8v*)&Bs[swi(wn * 32 + j * 16 + (lane & 15), kb)];
            #pragma unroll
            for (int i = 0; i < 2; ++i)
                #pragma unroll
                for (int j = 0; j < 2; ++j)
                    acc[i][j] = MF(a[i], bb[j], acc[i][j]);
        }
        if (t < 15) cur = nxt;
    }
    __syncthreads();
    #pragma unroll
    for (int j = 0; j < 2; ++j) {
        const int h = h0 + wn * 32 + j * 16 + (lane & 15);
        const float sc = gamma[h] * rsqrtf(var[h] + BN_EPS);
        const float of = (h_b[h] - mean[h]) * sc + beta[h];
        #pragma unroll
        for (int i = 0; i < 2; ++i)
            #pragma unroll
            for (int rr = 0; rr < 4; ++rr) {
                const int ml = wm * 32 + i * 16 + (lane >> 4) * 4 + rr;
                tsb[ml * 64 + wn * 32 + j * 16 + (lane & 15)] = f2b(fmaxf(0.f, acc[i][j][rr] * sc + of));
            }
    }
    __syncthreads();
    #pragma unroll
    for (int w = 0; w < 2; ++w)
        *(s8v*)&Xh[(size_t)(m0 + r) * LABh + h0 + kofs + w * 8] = *(const s8v*)&tsb[r * 64 + kofs + w * 8];
}

// ---------------------------------------------------------------------------
// k5: scP[z][b][c][o] partial over K range z.  tile 64(c)x64(o), split-K=4,
// dbuf+prefetch.  grid (16, 16): x = ct(0..3) + 4*z(0..3).
// ---------------------------------------------------------------------------
struct R5 { float4 ld[4]; s8v xh[2]; };

__global__ __launch_bounds__(256) void k5(const int* __restrict__ cand,
                                          const float* __restrict__ labD,
                                          const short* __restrict__ Xh,
                                          float* __restrict__ scP) {
    __shared__ __align__(16) char smem[33024];
    float (*ts)[68] = (float(*)[68])smem;
    int* cidx = (int*)(smem + 32768);
    const int tid = threadIdx.x, lane = tid & 63, wave = tid >> 6;
    const int wm = wave >> 1, wn = wave & 1;
    const int b = blockIdx.y;
    const int ct = blockIdx.x & 3, z = blockIdx.x >> 2;
    const int c0 = ct * 64;
    const int kbase = z * 256;
    if (tid < 64) cidx[tid] = cand[b * NCc + c0 + tid];
    __syncthreads();
    const int r = tid >> 2, kofs = (tid & 3) * 16;
    const int ci = cidx[r];
    const float* lrow = labD + (size_t)ci * LABh + kbase;
    const short* xrow = Xh + (size_t)(b * OSo + r) * LABh + kbase;
    f32x4 acc[2][2] = {};
    R5 cur, nxt;
    #pragma unroll
    for (int w = 0; w < 2; ++w) {
        cur.ld[2*w]   = *(const float4*)&lrow[kofs + w * 8];
        cur.ld[2*w+1] = *(const float4*)&lrow[kofs + w * 8 + 4];
        cur.xh[w]     = *(const s8v*)&xrow[kofs + w * 8];
    }
    #pragma unroll
    for (int t = 0; t < 4; ++t) {
        short* As = (short*)(smem + (t & 1) * 8192);
        short* Bs = (short*)(smem + 16384 + (t & 1) * 8192);
        #pragma unroll
        for (int w = 0; w < 2; ++w) {
            const float* f0 = (const float*)&cur.ld[2*w];
            s8v s;
            #pragma unroll
            for (int e = 0; e < 8; ++e) s[e] = f2b(f0[e]);
            *(s8v*)&As[swi(r, kofs + w * 8)] = s;
            *(s8v*)&Bs[swi(r, kofs + w * 8)] = cur.xh[w];
        }
        fastbar();
        if (t < 3) {
            const int k0 = (t + 1) * 64;
            #pragma unroll
            for (int w = 0; w < 2; ++w) {
                nxt.ld[2*w]   = *(const float4*)&lrow[k0 + kofs + w * 8];
                nxt.ld[2*w+1] = *(const float4*)&lrow[k0 + kofs + w * 8 + 4];
                nxt.xh[w]     = *(const s8v*)&xrow[k0 + kofs + w * 8];
            }
        }
        #pragma unroll
        for (int kk = 0; kk < 2; ++kk) {
            const int kb = kk * 32 + (lane >> 4) * 8;
            s8v a[2], bb[2];
            #pragma unroll
            for (int i = 0; i < 2; ++i)
                a[i] = *(const s8v*)&As[swi(wm * 32 + i * 16 + (lane & 15), kb)];
            #pragma unroll
            for (int j = 0; j < 2; ++j)
                bb[j] = *(const s8v*)&Bs[swi(wn * 32 + j * 16 + (lane & 15), kb)];
            #pragma unroll
            for (int i = 0; i < 2; ++i)
                #pragma unroll
                for (int j = 0; j < 2; ++j)
                    acc[i][j] = MF(a[i], bb[j], acc[i][j]);
        }
        if (t < 3) cur = nxt;
    }
    __syncthreads();
    #pragma unroll
    for (int i = 0; i < 2; ++i)
        #pragma unroll
        for (int j = 0; j < 2; ++j)
            #pragma unroll
            for (int rr = 0; rr < 4; ++rr)
                ts[wm * 32 + i * 16 + (lane >> 4) * 4 + rr][wn * 32 + j * 16 + (lane & 15)] = acc[i][j][rr];
    __syncthreads();
    const int oofs = (tid & 3) * 16;
    float* sp = scP + (size_t)z * ((size_t)Bb * NCc * OSo)
                    + ((size_t)b * NCc + c0 + r) * OSo + oofs;
    #pragma unroll
    for (int w = 0; w < 4; ++w)
        *(float4*)&sp[w * 4] = *(float4*)&ts[r][oofs + w * 4];
}

// ---------------------------------------------------------------------------
// k6: sum split-K partials of sc, softmax over o, out = alpha2^T @ Xh
// 512 blocks (8-candidate tiles), XCD-grouped by b.
// ---------------------------------------------------------------------------
__global__ __launch_bounds__(256) void k6(const float* __restrict__ scP,
                                          const short* __restrict__ Xh,
                                          float* __restrict__ out) {
    __shared__ float al[8][64];
    const int tid = threadIdx.x;
    const int id = blockIdx.x;
    const int slot = id >> 3;
    const int b = (id & 7) * 2 + (slot >> 5);
    const int c0 = (slot & 31) * 8;
    const size_t ZS = (size_t)Bb * NCc * OSo;
    {
        const int cl = tid >> 5, t32 = tid & 31;
        const float* srow = scP + ((size_t)b * NCc + c0 + cl) * OSo;
        float v[2];
        float m = -1e30f;
        #pragma unroll
        for (int j = 0; j < 2; ++j) {
            const int o = t32 + j * 32;
            v[j] = srow[o] + srow[ZS + o] + srow[2 * ZS + o] + srow[3 * ZS + o];
            m = fmaxf(m, v[j]);
        }
        #pragma unroll
        for (int off = 16; off; off >>= 1) m = fmaxf(m, __shfl_xor(m, off, 32));
        float s = 0.f;
        #pragma unroll
        for (int j = 0; j < 2; ++j) { v[j] = __expf(v[j] - m); s += v[j]; }
        #pragma unroll
        for (int off = 16; off; off >>= 1) s += __shfl_xor(s, off, 32);
        float inv = 1.f / s;
        #pragma unroll
        for (int j = 0; j < 2; ++j) al[cl][t32 + j * 32] = v[j] * inv;
    }
    __syncthreads();
    const short* xb = Xh + (size_t)b * OSo * LABh;
    float acc[8][4] = {};
    for (int o = 0; o < OSo; ++o) {
        s4v xv = *(const s4v*)&xb[(size_t)o * LABh + tid * 4];
        const float x0 = b2f(xv[0]), x1 = b2f(xv[1]), x2 = b2f(xv[2]), x3 = b2f(xv[3]);
        #pragma unroll
        for (int c = 0; c < 8; ++c) {
            const float w = al[c][o];
            acc[c][0] += w * x0; acc[c][1] += w * x1; acc[c][2] += w * x2; acc[c][3] += w * x3;
        }
    }
    #pragma unroll
    for (int c = 0; c < 8; ++c) {
        float4 v; v.x = acc[c][0]; v.y = acc[c][1]; v.z = acc[c][2]; v.w = acc[c][3];
        *(float4*)&out[((size_t)b * NCc + c0 + c) * LABh + tid * 4] = v;
    }
}

// ---------------------------------------------------------------------------
extern "C" void kernel_launch(void* const* d_in, const int* in_sizes, int n_in,
                              void* d_out, int out_size, void* d_ws, size_t ws_size,
                              hipStream_t stream) {
    (void)in_sizes; (void)n_in; (void)out_size; (void)ws_size;
    const float* X      = (const float*)d_in[0];
    const int*   cand   = (const int*)  d_in[1];
    const float* a_w    = (const float*)d_in[2];
    const float* a_b    = (const float*)d_in[3];
    const float* h_w    = (const float*)d_in[4];
    const float* h_b    = (const float*)d_in[5];
    const float* gamma  = (const float*)d_in[6];
    const float* beta   = (const float*)d_in[7];
    const float* mean   = (const float*)d_in[8];
    const float* var    = (const float*)d_in[9];
    const float* labDesc= (const float*)d_in[10];
    float* outp = (float*)d_out;

    char* ws = (char*)d_ws;
    float* St   = (float*)ws;                               // 8MB: St (k1/k2) then XpP (k3, 2x4MB)
    float* XpP  = St;
    short* aBf  = (short*)(ws + ((size_t)8  << 20));        // 4MB alpha bf16
    short* Xh   = (short*)(ws + ((size_t)12 << 20));        // 2MB
    float* scP  = (float*)(ws + ((size_t)14 << 20));        // 4MB (4 split-K partials)
    short* a_wT = (short*)(ws + ((size_t)18 << 20));        // 128KB
    short* h_wT = (short*)(ws + ((size_t)19 << 20));        // 2MB

    k0 <<<272,          256, 0, stream>>>(h_w, a_w, h_wT, a_wT);
    k1 <<<dim3(32, 16), 256, 0, stream>>>(X, a_wT, a_b, St);
    k2 <<<Bb * OSo,     256, 0, stream>>>(St, aBf);
    k3 <<<512,          256, 0, stream>>>(X, aBf, XpP);
    k4 <<<dim3(16, 16), 256, 0, stream>>>(XpP, h_wT, h_b, gamma, beta, mean, var, Xh);
    k5 <<<dim3(16, 16), 256, 0, stream>>>(cand, labDesc, Xh, scP);
    k6 <<<512,          256, 0, stream>>>(scP, Xh, outp);
}